// Round 4
// baseline (467.816 us; speedup 1.0000x reference)
//
#include <hip/hip_runtime.h>
#include <hip/hip_bf16.h>

// Problem constants (B=1)
#define T_SEQ 2048
#define D_MODEL 2048
#define NH 16
#define HDIM 128
#define RD_ROT 64

typedef __bf16 bf16x8 __attribute__((ext_vector_type(8)));
typedef float f32x4 __attribute__((ext_vector_type(4)));

__device__ __forceinline__ void async_copy16(const __bf16* g, __bf16* l) {
    __builtin_amdgcn_global_load_lds(
        (const __attribute__((address_space(1))) void*)g,
        (__attribute__((address_space(3))) void*)l, 16, 0, 0);
}

// ---------------------------------------------------------------------------
// Cast fp32 -> bf16 for the 5 GEMM operands (hidden, Wq, Wk, Wv, Wo).
// ---------------------------------------------------------------------------
__global__ __launch_bounds__(256) void cast_kernel(
    const float* __restrict__ s0, const float* __restrict__ s1, const float* __restrict__ s2,
    const float* __restrict__ s3, const float* __restrict__ s4,
    __bf16* __restrict__ d0, __bf16* __restrict__ d1, __bf16* __restrict__ d2,
    __bf16* __restrict__ d3, __bf16* __restrict__ d4)
{
    const float* s; __bf16* d;
    switch (blockIdx.y) {
        case 0: s = s0; d = d0; break;
        case 1: s = s1; d = d1; break;
        case 2: s = s2; d = d2; break;
        case 3: s = s3; d = d3; break;
        default: s = s4; d = d4; break;
    }
    size_t base = (size_t)blockIdx.x * D_MODEL + (size_t)threadIdx.x * 8;
    f32x4 a = *(const f32x4*)(s + base);
    f32x4 b = *(const f32x4*)(s + base + 4);
    bf16x8 o;
    #pragma unroll
    for (int i = 0; i < 4; i++) { o[i] = (__bf16)a[i]; o[i + 4] = (__bf16)b[i]; }
    *(bf16x8*)(d + base) = o;
}

// ---------------------------------------------------------------------------
// GEMM: C = A @ B^T, 128x128 tile, BK=32, LDS XOR-swizzled (conflict-free,
// verified round 3). blockIdx.z selects (B, C) so QKV runs as one launch.
// ---------------------------------------------------------------------------
__global__ __launch_bounds__(256) void gemm_bt_kernel(
    const __bf16* __restrict__ A,
    const __bf16* __restrict__ B0, const __bf16* __restrict__ B1, const __bf16* __restrict__ B2,
    __bf16* __restrict__ C0, __bf16* __restrict__ C1, __bf16* __restrict__ C2)
{
    constexpr int BM = 128, BK = 32, KD = D_MODEL;
    const __bf16* Bm = blockIdx.z == 0 ? B0 : (blockIdx.z == 1 ? B1 : B2);
    __bf16* Cm       = blockIdx.z == 0 ? C0 : (blockIdx.z == 1 ? C1 : C2);

    __shared__ __align__(16) __bf16 As[BM * BK];
    __shared__ __align__(16) __bf16 Bs[BM * BK];

    const int lane = threadIdx.x & 63;
    const int wave = threadIdx.x >> 6;
    const int r15  = lane & 15;
    const int quad = lane >> 4;
    const int bm = blockIdx.x * BM;
    const int bn = blockIdx.y * BM;
    const int wm = (wave >> 1) * 64;
    const int wn = (wave & 1) * 64;

    f32x4 acc[4][4] = {};

    const int srow = wave * 32 + (lane >> 2);
    const int sg   = (lane & 3) ^ ((lane >> 2) & 3);

    for (int k0 = 0; k0 < KD; k0 += BK) {
        async_copy16(A  + (size_t)(bm + srow)      * KD + k0 + sg * 8, &As[wave * 1024]);
        async_copy16(A  + (size_t)(bm + srow + 16) * KD + k0 + sg * 8, &As[wave * 1024 + 512]);
        async_copy16(Bm + (size_t)(bn + srow)      * KD + k0 + sg * 8, &Bs[wave * 1024]);
        async_copy16(Bm + (size_t)(bn + srow + 16) * KD + k0 + sg * 8, &Bs[wave * 1024 + 512]);
        __syncthreads();

        bf16x8 av[4], bv[4];
        #pragma unroll
        for (int mt = 0; mt < 4; mt++)
            av[mt] = *(const bf16x8*)&As[(wm + mt * 16 + r15) * 32 + ((quad ^ (r15 & 3)) << 3)];
        #pragma unroll
        for (int nt = 0; nt < 4; nt++)
            bv[nt] = *(const bf16x8*)&Bs[(wn + nt * 16 + r15) * 32 + ((quad ^ (r15 & 3)) << 3)];
        #pragma unroll
        for (int mt = 0; mt < 4; mt++)
            #pragma unroll
            for (int nt = 0; nt < 4; nt++)
                acc[mt][nt] = __builtin_amdgcn_mfma_f32_16x16x32_bf16(av[mt], bv[nt], acc[mt][nt], 0, 0, 0);
        __syncthreads();
    }

    #pragma unroll
    for (int mt = 0; mt < 4; mt++) {
        #pragma unroll
        for (int r = 0; r < 4; r++) {
            size_t row = bm + wm + mt * 16 + quad * 4 + r;
            #pragma unroll
            for (int nt = 0; nt < 4; nt++) {
                size_t col = bn + wn + nt * 16 + r15;
                Cm[row * D_MODEL + col] = (__bf16)acc[mt][nt][r];
            }
        }
    }
}

// ---------------------------------------------------------------------------
// Split-K GEMM for the final projection (fp32 atomic epilogue).
// ---------------------------------------------------------------------------
__global__ __launch_bounds__(256) void gemm_bt_splitk_kernel(
    const __bf16* __restrict__ A, const __bf16* __restrict__ Bm, float* __restrict__ C)
{
    constexpr int BM = 128, BK = 32, KD = D_MODEL;
    __shared__ __align__(16) __bf16 As[BM * BK];
    __shared__ __align__(16) __bf16 Bs[BM * BK];

    const int lane = threadIdx.x & 63;
    const int wave = threadIdx.x >> 6;
    const int r15  = lane & 15;
    const int quad = lane >> 4;
    const int bm = blockIdx.x * BM;
    const int bn = blockIdx.y * BM;
    const int wm = (wave >> 1) * 64;
    const int wn = (wave & 1) * 64;
    const int kbase = blockIdx.z * (KD / 2);

    f32x4 acc[4][4] = {};
    const int srow = wave * 32 + (lane >> 2);
    const int sg   = (lane & 3) ^ ((lane >> 2) & 3);

    for (int k0 = kbase; k0 < kbase + KD / 2; k0 += BK) {
        async_copy16(A  + (size_t)(bm + srow)      * KD + k0 + sg * 8, &As[wave * 1024]);
        async_copy16(A  + (size_t)(bm + srow + 16) * KD + k0 + sg * 8, &As[wave * 1024 + 512]);
        async_copy16(Bm + (size_t)(bn + srow)      * KD + k0 + sg * 8, &Bs[wave * 1024]);
        async_copy16(Bm + (size_t)(bn + srow + 16) * KD + k0 + sg * 8, &Bs[wave * 1024 + 512]);
        __syncthreads();

        bf16x8 av[4], bv[4];
        #pragma unroll
        for (int mt = 0; mt < 4; mt++)
            av[mt] = *(const bf16x8*)&As[(wm + mt * 16 + r15) * 32 + ((quad ^ (r15 & 3)) << 3)];
        #pragma unroll
        for (int nt = 0; nt < 4; nt++)
            bv[nt] = *(const bf16x8*)&Bs[(wn + nt * 16 + r15) * 32 + ((quad ^ (r15 & 3)) << 3)];
        #pragma unroll
        for (int mt = 0; mt < 4; mt++)
            #pragma unroll
            for (int nt = 0; nt < 4; nt++)
                acc[mt][nt] = __builtin_amdgcn_mfma_f32_16x16x32_bf16(av[mt], bv[nt], acc[mt][nt], 0, 0, 0);
        __syncthreads();
    }

    #pragma unroll
    for (int mt = 0; mt < 4; mt++) {
        #pragma unroll
        for (int r = 0; r < 4; r++) {
            size_t row = bm + wm + mt * 16 + quad * 4 + r;
            #pragma unroll
            for (int nt = 0; nt < 4; nt++) {
                size_t col = bn + wn + nt * 16 + r15;
                atomicAdd(&C[row * D_MODEL + col], acc[mt][nt][r]);
            }
        }
    }
}

// ---------------------------------------------------------------------------
// Preproc q/k: conv(K=4)+SiLU+RMSNorm+RoPE, pure-register.
// q is pre-scaled by 1/sqrt(HD); the reference's outer negation of the rotary
// dims is dropped (it negates the same dims of q AND k, so it cancels in qk^T).
// ---------------------------------------------------------------------------
__global__ __launch_bounds__(256) void preproc_qk_kernel(
    const __bf16* __restrict__ q_raw, const __bf16* __restrict__ k_raw,
    const float* __restrict__ cwq, const float* __restrict__ cwk,
    const float* __restrict__ qnw, const float* __restrict__ knw,
    const float* __restrict__ cosb, const float* __restrict__ sinb,
    __bf16* __restrict__ q_proc, __bf16* __restrict__ k_proc)
{
    const int t = blockIdx.x;
    const int which = blockIdx.y;
    const __bf16* X = which ? k_raw : q_raw;
    const float*  W = which ? cwk : cwq;
    const float*  nw = which ? knw : qnw;
    __bf16* P = which ? k_proc : q_proc;
    const float SC = which ? 1.0f : 0.08838834764831845f;  // 1/sqrt(128) folded into q

    const int tid = threadIdx.x;
    const int c0  = tid * 8;
    const int h   = tid >> 4;
    const int dl0 = (tid & 15) * 8;

    f32x4 wv[8];
    #pragma unroll
    for (int i = 0; i < 8; i++) wv[i] = *(const f32x4*)&W[(c0 + i) * 4];

    float acc[8] = {};
    #pragma unroll
    for (int j = 0; j < 4; j++) {
        int tt = t + j - 3;
        if (tt >= 0) {
            bf16x8 xv = *(const bf16x8*)&X[(size_t)tt * D_MODEL + c0];
            #pragma unroll
            for (int i = 0; i < 8; i++) acc[i] += (float)xv[i] * wv[i][j];
        }
    }
    float sil[8], ss = 0.f;
    #pragma unroll
    for (int i = 0; i < 8; i++) {
        float s = acc[i] / (1.f + __expf(-acc[i]));
        sil[i] = s; ss += s * s;
    }
    #pragma unroll
    for (int off = 1; off < 16; off <<= 1) ss += __shfl_xor(ss, off);
    float inv = rsqrtf(ss * (1.f / 128.f) + 1e-5f);

    f32x4 nv0 = *(const f32x4*)&nw[dl0];
    f32x4 nv1 = *(const f32x4*)&nw[dl0 + 4];
    float yn[8];
    #pragma unroll
    for (int i = 0; i < 8; i++) yn[i] = sil[i] * inv * (i < 4 ? nv0[i] : nv1[i - 4]);

    float partner[8];
    #pragma unroll
    for (int i = 0; i < 8; i++) partner[i] = __shfl_xor(yn[i], 4);  // dl ^ 32

    bf16x8 o;
    if (dl0 < RD_ROT) {
        f32x4 cv0 = *(const f32x4*)&cosb[t * RD_ROT + dl0];
        f32x4 cv1 = *(const f32x4*)&cosb[t * RD_ROT + dl0 + 4];
        f32x4 sv0 = *(const f32x4*)&sinb[t * RD_ROT + dl0];
        f32x4 sv1 = *(const f32x4*)&sinb[t * RD_ROT + dl0 + 4];
        #pragma unroll
        for (int i = 0; i < 8; i++) {
            int dl = dl0 + i;
            float c = i < 4 ? cv0[i] : cv1[i - 4];
            float s = i < 4 ? sv0[i] : sv1[i - 4];
            float rot = (dl < 32) ? -partner[i] : partner[i];  // rotate_half
            o[i] = (__bf16)((yn[i] * c + rot * s) * SC);
        }
    } else {
        #pragma unroll
        for (int i = 0; i < 8; i++) o[i] = (__bf16)(yn[i] * SC);
    }
    *(bf16x8*)&P[((size_t)h * T_SEQ + t) * HDIM + dl0] = o;
}

// ---------------------------------------------------------------------------
// Preproc v: conv+SiLU, transposed (H, HD, T) store, bf16x8 per thread.
// ---------------------------------------------------------------------------
__global__ __launch_bounds__(128) void preproc_v_kernel(
    const __bf16* __restrict__ v_raw, const float* __restrict__ cwv,
    __bf16* __restrict__ v_t)
{
    const int t0 = blockIdx.x * 8;
    const int h = blockIdx.y;
    const int dl = threadIdx.x;
    const int d = h * HDIM + dl;

    f32x4 wv = *(const f32x4*)&cwv[d * 4];
    float x[11];
    #pragma unroll
    for (int m = 0; m < 11; m++) {
        int tt = t0 - 3 + m;
        x[m] = (tt >= 0) ? (float)v_raw[(size_t)tt * D_MODEL + d] : 0.f;
    }
    bf16x8 o;
    #pragma unroll
    for (int r = 0; r < 8; r++) {
        float y = x[r] * wv[0] + x[r + 1] * wv[1] + x[r + 2] * wv[2] + x[r + 3] * wv[3];
        o[r] = (__bf16)(y / (1.f + __expf(-y)));
    }
    *(bf16x8*)&v_t[((size_t)h * HDIM + dl) * T_SEQ + t0] = o;
}

// ---------------------------------------------------------------------------
// Flash attention, causal. Barrier-free K/V path: B-fragments for QK^T and PV
// are loaded DIRECTLY from global (16B contiguous in the layouts we staged) —
// no K/V LDS, no __syncthreads in the k-loop. 2 waves/block, 32 q-rows/wave
// (each kf/vf feeds 2 MFMAs). Only P round-trips LDS (wave-private region,
// stride 72 = 144B: 16B-aligned, reads conflict-free). Online softmax with
// deferred l-reduction. Q is pre-scaled by 1/sqrt(HD) in preproc.
// ---------------------------------------------------------------------------
__global__ __launch_bounds__(128, 2) void attn_kernel(
    const __bf16* __restrict__ Qp,   // (H, T, HD), pre-scaled
    const __bf16* __restrict__ Kp,   // (H, T, HD)
    const __bf16* __restrict__ Vt,   // (H, HD, T)
    __bf16* __restrict__ Op)         // (T, D)
{
    constexpr int TK = 64, PSTR = 72;
    __shared__ __align__(16) __bf16 Ps[64 * PSTR];

    const int lane = threadIdx.x & 63;
    const int wave = threadIdx.x >> 6;   // 0..1
    const int r15  = lane & 15;
    const int quad = lane >> 4;
    const int h = blockIdx.y;
    // pair heavy/light tiles across the dispatch (block b with b+256)
    const int qi = (blockIdx.y & 8) ? ((int)gridDim.x - 1 - (int)blockIdx.x) : (int)blockIdx.x;
    const int q0 = qi * 64;
    const int m0 = wave * 32;            // wave-private 32 q-rows

    // Q fragments: 2 m-tiles x 4 k-frags (A-layout: m=lane&15, k=quad*8+j)
    bf16x8 qf[2][4];
    #pragma unroll
    for (int mt = 0; mt < 2; mt++) {
        const __bf16* qb = Qp + ((size_t)h * T_SEQ + q0 + m0 + mt * 16 + r15) * HDIM + quad * 8;
        #pragma unroll
        for (int s = 0; s < 4; s++) qf[mt][s] = *(const bf16x8*)(qb + s * 32);
    }

    const __bf16* Kb = Kp + (size_t)h * T_SEQ * HDIM;
    const __bf16* Vb = Vt + (size_t)h * HDIM * T_SEQ;

    f32x4 oacc[2][8] = {};
    float mrow[2][4], lsum[2][4];
    #pragma unroll
    for (int mt = 0; mt < 2; mt++)
        #pragma unroll
        for (int r = 0; r < 4; r++) { mrow[mt][r] = -1e30f; lsum[mt][r] = 0.f; }

    const int ntk = qi + 1;
    for (int it = 0; it < ntk; it++) {
        const int tk0 = it * TK;
        const bool last = (it == ntk - 1);

        // ---- S = Q K^T : kf direct from global (B-layout = 16B along HD) ----
        f32x4 sacc[2][4] = {};
        #pragma unroll
        for (int s = 0; s < 4; s++) {
            bf16x8 kf[4];
            #pragma unroll
            for (int nt = 0; nt < 4; nt++)
                kf[nt] = *(const bf16x8*)(Kb + (size_t)(tk0 + nt * 16 + r15) * HDIM + s * 32 + quad * 8);
            #pragma unroll
            for (int nt = 0; nt < 4; nt++)
                #pragma unroll
                for (int mt = 0; mt < 2; mt++)
                    sacc[mt][nt] = __builtin_amdgcn_mfma_f32_16x16x32_bf16(qf[mt][s], kf[nt], sacc[mt][nt], 0, 0, 0);
        }

        // ---- online softmax (mask only on the diagonal tile) ----
        float alpha[2][4];
        #pragma unroll
        for (int mt = 0; mt < 2; mt++) {
            #pragma unroll
            for (int r = 0; r < 4; r++) {
                if (last) {
                    int qrow = q0 + m0 + mt * 16 + quad * 4 + r;
                    #pragma unroll
                    for (int nt = 0; nt < 4; nt++) {
                        int kcol = tk0 + nt * 16 + r15;
                        if (kcol > qrow) sacc[mt][nt][r] = -1e30f;
                    }
                }
                float tm = fmaxf(fmaxf(sacc[mt][0][r], sacc[mt][1][r]),
                                 fmaxf(sacc[mt][2][r], sacc[mt][3][r]));
                #pragma unroll
                for (int off = 1; off < 16; off <<= 1) tm = fmaxf(tm, __shfl_xor(tm, off));
                float mn = fmaxf(mrow[mt][r], tm);
                float a = __expf(mrow[mt][r] - mn);
                mrow[mt][r] = mn;
                alpha[mt][r] = a;
                float ps = 0.f;
                #pragma unroll
                for (int nt = 0; nt < 4; nt++) {
                    float p = __expf(sacc[mt][nt][r] - mn);
                    sacc[mt][nt][r] = p;          // reuse sacc as P
                    ps += p;
                }
                lsum[mt][r] = lsum[mt][r] * a + ps;   // per-lane partial; reduced at end
            }
        }
        #pragma unroll
        for (int mt = 0; mt < 2; mt++)
            #pragma unroll
            for (int nt = 0; nt < 8; nt++)
                #pragma unroll
                for (int r = 0; r < 4; r++) oacc[mt][nt][r] *= alpha[mt][r];

        // ---- P: C-layout -> LDS (wave-private rows, no barrier) ----
        #pragma unroll
        for (int mt = 0; mt < 2; mt++)
            #pragma unroll
            for (int nt = 0; nt < 4; nt++)
                #pragma unroll
                for (int r = 0; r < 4; r++)
                    Ps[(m0 + mt * 16 + quad * 4 + r) * PSTR + nt * 16 + r15] = (__bf16)sacc[mt][nt][r];

        // ---- O += P V : vf direct from global (16B along T) ----
        #pragma unroll
        for (int s2 = 0; s2 < 2; s2++) {
            bf16x8 pf[2];
            #pragma unroll
            for (int mt = 0; mt < 2; mt++)
                pf[mt] = *(const bf16x8*)&Ps[(m0 + mt * 16 + r15) * PSTR + s2 * 32 + quad * 8];
            #pragma unroll
            for (int nt = 0; nt < 8; nt++) {
                bf16x8 vf = *(const bf16x8*)(Vb + (size_t)(nt * 16 + r15) * T_SEQ + tk0 + s2 * 32 + quad * 8);
                #pragma unroll
                for (int mt = 0; mt < 2; mt++)
                    oacc[mt][nt] = __builtin_amdgcn_mfma_f32_16x16x32_bf16(pf[mt], vf, oacc[mt][nt], 0, 0, 0);
            }
        }
    }

    // ---- epilogue: reduce l across the 16 lanes of each row, scale, store ----
    #pragma unroll
    for (int mt = 0; mt < 2; mt++) {
        #pragma unroll
        for (int r = 0; r < 4; r++) {
            float l = lsum[mt][r];
            #pragma unroll
            for (int off = 1; off < 16; off <<= 1) l += __shfl_xor(l, off);
            float inv = 1.0f / l;
            size_t row = q0 + m0 + mt * 16 + quad * 4 + r;
            #pragma unroll
            for (int nt = 0; nt < 8; nt++)
                Op[row * D_MODEL + h * HDIM + nt * 16 + r15] = (__bf16)(oacc[mt][nt][r] * inv);
        }
    }
}

// ---------------------------------------------------------------------------
extern "C" void kernel_launch(void* const* d_in, const int* in_sizes, int n_in,
                              void* d_out, int out_size, void* d_ws, size_t ws_size,
                              hipStream_t stream) {
    (void)in_sizes; (void)n_in; (void)out_size; (void)ws_size;
    const float* hidden = (const float*)d_in[0];
    const float* cosb   = (const float*)d_in[1];
    const float* sinb   = (const float*)d_in[2];
    const float* Wq     = (const float*)d_in[3];
    const float* Wk     = (const float*)d_in[4];
    const float* Wv     = (const float*)d_in[5];
    const float* Wo     = (const float*)d_in[6];
    const float* cwq    = (const float*)d_in[7];
    const float* cwk    = (const float*)d_in[8];
    const float* cwv    = (const float*)d_in[9];
    const float* qnw    = (const float*)d_in[10];
    const float* knw    = (const float*)d_in[11];

    const size_t NEL = (size_t)T_SEQ * D_MODEL;
    __bf16* ws = (__bf16*)d_ws;
    __bf16* h_bf   = ws + 0 * NEL;   // later reused as attn_b
    __bf16* Wq_bf  = ws + 1 * NEL;   // later reused as q_proc
    __bf16* Wk_bf  = ws + 2 * NEL;   // later reused as k_proc
    __bf16* Wv_bf  = ws + 3 * NEL;   // later reused as v_t
    __bf16* Wo_bf  = ws + 4 * NEL;   // persists to final GEMM
    __bf16* q_raw  = ws + 5 * NEL;
    __bf16* k_raw  = ws + 6 * NEL;
    __bf16* v_raw  = ws + 7 * NEL;
    __bf16* q_proc = Wq_bf;
    __bf16* k_proc = Wk_bf;
    __bf16* v_t    = Wv_bf;
    __bf16* attn_b = h_bf;
    float*  out    = (float*)d_out;

    // 0. cast fp32 inputs to bf16
    cast_kernel<<<dim3(T_SEQ, 5), 256, 0, stream>>>(hidden, Wq, Wk, Wv, Wo,
                                                    h_bf, Wq_bf, Wk_bf, Wv_bf, Wo_bf);
    // 1. q,k,v = hidden @ {Wq,Wk,Wv}^T (batched)
    gemm_bt_kernel<<<dim3(16, 16, 3), 256, 0, stream>>>(
        h_bf, Wq_bf, Wk_bf, Wv_bf, q_raw, k_raw, v_raw);
    // 2. preproc
    preproc_qk_kernel<<<dim3(T_SEQ, 2), 256, 0, stream>>>(
        q_raw, k_raw, cwq, cwk, qnw, knw, cosb, sinb, q_proc, k_proc);
    preproc_v_kernel<<<dim3(T_SEQ / 8, NH), 128, 0, stream>>>(v_raw, cwv, v_t);
    // 3. causal flash attention (barrier-free K/V)
    attn_kernel<<<dim3(T_SEQ / 64, NH), 128, 0, stream>>>(q_proc, k_proc, v_t, attn_b);
    // 4. out = attn @ Wo^T, split-K x2 with fp32 atomic epilogue
    hipMemsetAsync(d_out, 0, NEL * sizeof(float), stream);
    gemm_bt_splitk_kernel<<<dim3(16, 16, 2), 256, 0, stream>>>(attn_b, Wo_bf, out);
}

// Round 5
// 345.225 us; speedup vs baseline: 1.3551x; 1.3551x over previous
//
#include <hip/hip_runtime.h>
#include <hip/hip_bf16.h>

// Problem constants (B=1)
#define T_SEQ 2048
#define D_MODEL 2048
#define NH 16
#define HDIM 128
#define RD_ROT 64

typedef __bf16 bf16x8 __attribute__((ext_vector_type(8)));
typedef float f32x4 __attribute__((ext_vector_type(4)));

__device__ __forceinline__ void async_copy16(const __bf16* g, __bf16* l) {
    __builtin_amdgcn_global_load_lds(
        (const __attribute__((address_space(1))) void*)g,
        (__attribute__((address_space(3))) void*)l, 16, 0, 0);
}

// ---------------------------------------------------------------------------
// Cast fp32 -> bf16 for the 5 GEMM operands (hidden, Wq, Wk, Wv, Wo).
// ---------------------------------------------------------------------------
__global__ __launch_bounds__(256) void cast_kernel(
    const float* __restrict__ s0, const float* __restrict__ s1, const float* __restrict__ s2,
    const float* __restrict__ s3, const float* __restrict__ s4,
    __bf16* __restrict__ d0, __bf16* __restrict__ d1, __bf16* __restrict__ d2,
    __bf16* __restrict__ d3, __bf16* __restrict__ d4)
{
    const float* s; __bf16* d;
    switch (blockIdx.y) {
        case 0: s = s0; d = d0; break;
        case 1: s = s1; d = d1; break;
        case 2: s = s2; d = d2; break;
        case 3: s = s3; d = d3; break;
        default: s = s4; d = d4; break;
    }
    size_t base = (size_t)blockIdx.x * D_MODEL + (size_t)threadIdx.x * 8;
    f32x4 a = *(const f32x4*)(s + base);
    f32x4 b = *(const f32x4*)(s + base + 4);
    bf16x8 o;
    #pragma unroll
    for (int i = 0; i < 4; i++) { o[i] = (__bf16)a[i]; o[i + 4] = (__bf16)b[i]; }
    *(bf16x8*)(d + base) = o;
}

// ---------------------------------------------------------------------------
// GEMM: C = A @ B^T, 128x128 tile, BK=32, LDS XOR-swizzled (conflict-free,
// verified round 3). blockIdx.z selects (B, C) so QKV runs as one launch.
// ---------------------------------------------------------------------------
__global__ __launch_bounds__(256) void gemm_bt_kernel(
    const __bf16* __restrict__ A,
    const __bf16* __restrict__ B0, const __bf16* __restrict__ B1, const __bf16* __restrict__ B2,
    __bf16* __restrict__ C0, __bf16* __restrict__ C1, __bf16* __restrict__ C2)
{
    constexpr int BM = 128, BK = 32, KD = D_MODEL;
    const __bf16* Bm = blockIdx.z == 0 ? B0 : (blockIdx.z == 1 ? B1 : B2);
    __bf16* Cm       = blockIdx.z == 0 ? C0 : (blockIdx.z == 1 ? C1 : C2);

    __shared__ __align__(16) __bf16 As[BM * BK];
    __shared__ __align__(16) __bf16 Bs[BM * BK];

    const int lane = threadIdx.x & 63;
    const int wave = threadIdx.x >> 6;
    const int r15  = lane & 15;
    const int quad = lane >> 4;
    const int bm = blockIdx.x * BM;
    const int bn = blockIdx.y * BM;
    const int wm = (wave >> 1) * 64;
    const int wn = (wave & 1) * 64;

    f32x4 acc[4][4] = {};

    const int srow = wave * 32 + (lane >> 2);
    const int sg   = (lane & 3) ^ ((lane >> 2) & 3);

    for (int k0 = 0; k0 < KD; k0 += BK) {
        async_copy16(A  + (size_t)(bm + srow)      * KD + k0 + sg * 8, &As[wave * 1024]);
        async_copy16(A  + (size_t)(bm + srow + 16) * KD + k0 + sg * 8, &As[wave * 1024 + 512]);
        async_copy16(Bm + (size_t)(bn + srow)      * KD + k0 + sg * 8, &Bs[wave * 1024]);
        async_copy16(Bm + (size_t)(bn + srow + 16) * KD + k0 + sg * 8, &Bs[wave * 1024 + 512]);
        __syncthreads();

        bf16x8 av[4], bv[4];
        #pragma unroll
        for (int mt = 0; mt < 4; mt++)
            av[mt] = *(const bf16x8*)&As[(wm + mt * 16 + r15) * 32 + ((quad ^ (r15 & 3)) << 3)];
        #pragma unroll
        for (int nt = 0; nt < 4; nt++)
            bv[nt] = *(const bf16x8*)&Bs[(wn + nt * 16 + r15) * 32 + ((quad ^ (r15 & 3)) << 3)];
        #pragma unroll
        for (int mt = 0; mt < 4; mt++)
            #pragma unroll
            for (int nt = 0; nt < 4; nt++)
                acc[mt][nt] = __builtin_amdgcn_mfma_f32_16x16x32_bf16(av[mt], bv[nt], acc[mt][nt], 0, 0, 0);
        __syncthreads();
    }

    #pragma unroll
    for (int mt = 0; mt < 4; mt++) {
        #pragma unroll
        for (int r = 0; r < 4; r++) {
            size_t row = bm + wm + mt * 16 + quad * 4 + r;
            #pragma unroll
            for (int nt = 0; nt < 4; nt++) {
                size_t col = bn + wn + nt * 16 + r15;
                Cm[row * D_MODEL + col] = (__bf16)acc[mt][nt][r];
            }
        }
    }
}

// ---------------------------------------------------------------------------
// Split-K GEMM for the final projection (fp32 atomic epilogue).
// ---------------------------------------------------------------------------
__global__ __launch_bounds__(256) void gemm_bt_splitk_kernel(
    const __bf16* __restrict__ A, const __bf16* __restrict__ Bm, float* __restrict__ C)
{
    constexpr int BM = 128, BK = 32, KD = D_MODEL;
    __shared__ __align__(16) __bf16 As[BM * BK];
    __shared__ __align__(16) __bf16 Bs[BM * BK];

    const int lane = threadIdx.x & 63;
    const int wave = threadIdx.x >> 6;
    const int r15  = lane & 15;
    const int quad = lane >> 4;
    const int bm = blockIdx.x * BM;
    const int bn = blockIdx.y * BM;
    const int wm = (wave >> 1) * 64;
    const int wn = (wave & 1) * 64;
    const int kbase = blockIdx.z * (KD / 2);

    f32x4 acc[4][4] = {};
    const int srow = wave * 32 + (lane >> 2);
    const int sg   = (lane & 3) ^ ((lane >> 2) & 3);

    for (int k0 = kbase; k0 < kbase + KD / 2; k0 += BK) {
        async_copy16(A  + (size_t)(bm + srow)      * KD + k0 + sg * 8, &As[wave * 1024]);
        async_copy16(A  + (size_t)(bm + srow + 16) * KD + k0 + sg * 8, &As[wave * 1024 + 512]);
        async_copy16(Bm + (size_t)(bn + srow)      * KD + k0 + sg * 8, &Bs[wave * 1024]);
        async_copy16(Bm + (size_t)(bn + srow + 16) * KD + k0 + sg * 8, &Bs[wave * 1024 + 512]);
        __syncthreads();

        bf16x8 av[4], bv[4];
        #pragma unroll
        for (int mt = 0; mt < 4; mt++)
            av[mt] = *(const bf16x8*)&As[(wm + mt * 16 + r15) * 32 + ((quad ^ (r15 & 3)) << 3)];
        #pragma unroll
        for (int nt = 0; nt < 4; nt++)
            bv[nt] = *(const bf16x8*)&Bs[(wn + nt * 16 + r15) * 32 + ((quad ^ (r15 & 3)) << 3)];
        #pragma unroll
        for (int mt = 0; mt < 4; mt++)
            #pragma unroll
            for (int nt = 0; nt < 4; nt++)
                acc[mt][nt] = __builtin_amdgcn_mfma_f32_16x16x32_bf16(av[mt], bv[nt], acc[mt][nt], 0, 0, 0);
        __syncthreads();
    }

    #pragma unroll
    for (int mt = 0; mt < 4; mt++) {
        #pragma unroll
        for (int r = 0; r < 4; r++) {
            size_t row = bm + wm + mt * 16 + quad * 4 + r;
            #pragma unroll
            for (int nt = 0; nt < 4; nt++) {
                size_t col = bn + wn + nt * 16 + r15;
                atomicAdd(&C[row * D_MODEL + col], acc[mt][nt][r]);
            }
        }
    }
}

// ---------------------------------------------------------------------------
// Preproc q/k: conv(K=4)+SiLU+RMSNorm+RoPE, pure-register.
// q pre-scaled by 1/sqrt(HD); outer rotary negation dropped (cancels in qk^T).
// ---------------------------------------------------------------------------
__global__ __launch_bounds__(256) void preproc_qk_kernel(
    const __bf16* __restrict__ q_raw, const __bf16* __restrict__ k_raw,
    const float* __restrict__ cwq, const float* __restrict__ cwk,
    const float* __restrict__ qnw, const float* __restrict__ knw,
    const float* __restrict__ cosb, const float* __restrict__ sinb,
    __bf16* __restrict__ q_proc, __bf16* __restrict__ k_proc)
{
    const int t = blockIdx.x;
    const int which = blockIdx.y;
    const __bf16* X = which ? k_raw : q_raw;
    const float*  W = which ? cwk : cwq;
    const float*  nw = which ? knw : qnw;
    __bf16* P = which ? k_proc : q_proc;
    const float SC = which ? 1.0f : 0.08838834764831845f;  // 1/sqrt(128) folded into q

    const int tid = threadIdx.x;
    const int c0  = tid * 8;
    const int h   = tid >> 4;
    const int dl0 = (tid & 15) * 8;

    f32x4 wv[8];
    #pragma unroll
    for (int i = 0; i < 8; i++) wv[i] = *(const f32x4*)&W[(c0 + i) * 4];

    float acc[8] = {};
    #pragma unroll
    for (int j = 0; j < 4; j++) {
        int tt = t + j - 3;
        if (tt >= 0) {
            bf16x8 xv = *(const bf16x8*)&X[(size_t)tt * D_MODEL + c0];
            #pragma unroll
            for (int i = 0; i < 8; i++) acc[i] += (float)xv[i] * wv[i][j];
        }
    }
    float sil[8], ss = 0.f;
    #pragma unroll
    for (int i = 0; i < 8; i++) {
        float s = acc[i] / (1.f + __expf(-acc[i]));
        sil[i] = s; ss += s * s;
    }
    #pragma unroll
    for (int off = 1; off < 16; off <<= 1) ss += __shfl_xor(ss, off);
    float inv = rsqrtf(ss * (1.f / 128.f) + 1e-5f);

    f32x4 nv0 = *(const f32x4*)&nw[dl0];
    f32x4 nv1 = *(const f32x4*)&nw[dl0 + 4];
    float yn[8];
    #pragma unroll
    for (int i = 0; i < 8; i++) yn[i] = sil[i] * inv * (i < 4 ? nv0[i] : nv1[i - 4]);

    float partner[8];
    #pragma unroll
    for (int i = 0; i < 8; i++) partner[i] = __shfl_xor(yn[i], 4);  // dl ^ 32

    bf16x8 o;
    if (dl0 < RD_ROT) {
        f32x4 cv0 = *(const f32x4*)&cosb[t * RD_ROT + dl0];
        f32x4 cv1 = *(const f32x4*)&cosb[t * RD_ROT + dl0 + 4];
        f32x4 sv0 = *(const f32x4*)&sinb[t * RD_ROT + dl0];
        f32x4 sv1 = *(const f32x4*)&sinb[t * RD_ROT + dl0 + 4];
        #pragma unroll
        for (int i = 0; i < 8; i++) {
            int dl = dl0 + i;
            float c = i < 4 ? cv0[i] : cv1[i - 4];
            float s = i < 4 ? sv0[i] : sv1[i - 4];
            float rot = (dl < 32) ? -partner[i] : partner[i];  // rotate_half
            o[i] = (__bf16)((yn[i] * c + rot * s) * SC);
        }
    } else {
        #pragma unroll
        for (int i = 0; i < 8; i++) o[i] = (__bf16)(yn[i] * SC);
    }
    *(bf16x8*)&P[((size_t)h * T_SEQ + t) * HDIM + dl0] = o;
}

// ---------------------------------------------------------------------------
// Preproc v: conv+SiLU, transposed (H, HD, T) store, bf16x8 per thread.
// ---------------------------------------------------------------------------
__global__ __launch_bounds__(128) void preproc_v_kernel(
    const __bf16* __restrict__ v_raw, const float* __restrict__ cwv,
    __bf16* __restrict__ v_t)
{
    const int t0 = blockIdx.x * 8;
    const int h = blockIdx.y;
    const int dl = threadIdx.x;
    const int d = h * HDIM + dl;

    f32x4 wv = *(const f32x4*)&cwv[d * 4];
    float x[11];
    #pragma unroll
    for (int m = 0; m < 11; m++) {
        int tt = t0 - 3 + m;
        x[m] = (tt >= 0) ? (float)v_raw[(size_t)tt * D_MODEL + d] : 0.f;
    }
    bf16x8 o;
    #pragma unroll
    for (int r = 0; r < 8; r++) {
        float y = x[r] * wv[0] + x[r + 1] * wv[1] + x[r + 2] * wv[2] + x[r + 3] * wv[3];
        o[r] = (__bf16)(y / (1.f + __expf(-y)));
    }
    *(bf16x8*)&v_t[((size_t)h * HDIM + dl) * T_SEQ + t0] = o;
}

// ---------------------------------------------------------------------------
// Flash attention, causal — round-3 structure + DOUBLE-BUFFERED K/V staging.
// 4 waves x 16 q-rows. stage(it+1) is issued right after the barrier, so the
// next barrier's vmcnt drain targets loads issued a full compute-phase ago.
// K/V LDS XOR-swizzled (0 conflicts, verified r3). Ps stride-72, wave-private,
// no barrier. Deferred l-reduction; mask only on the diagonal tile; Q
// pre-scaled by 1/sqrt(HD).
// ---------------------------------------------------------------------------
__global__ __launch_bounds__(256, 2) void attn_kernel(
    const __bf16* __restrict__ Qp,   // (H, T, HD), pre-scaled
    const __bf16* __restrict__ Kp,   // (H, T, HD)
    const __bf16* __restrict__ Vt,   // (H, HD, T)
    __bf16* __restrict__ Op)         // (T, D)
{
    constexpr int TK = 64, PSTR = 72;
    __shared__ __align__(16) __bf16 Ks[2][TK * HDIM];   // 2 x 16 KB
    __shared__ __align__(16) __bf16 Vs[2][HDIM * TK];   // 2 x 16 KB
    __shared__ __align__(16) __bf16 Ps[64 * PSTR];      // 9 KB

    const int lane = threadIdx.x & 63;
    const int wave = threadIdx.x >> 6;
    const int r15  = lane & 15;
    const int quad = lane >> 4;
    const int h = blockIdx.y;
    // pair heavy/light tiles across the dispatch (2 blocks/CU round-robin)
    const int qi = (blockIdx.y & 8) ? ((int)gridDim.x - 1 - (int)blockIdx.x) : (int)blockIdx.x;
    const int q0 = qi * TK;

    const __bf16* Kb = Kp + (size_t)h * T_SEQ * HDIM;
    const __bf16* Vb = Vt + (size_t)h * HDIM * T_SEQ;

    // staging geometry (per wave: 4 K-chunks of 4 rows, 4 V-chunks of 8 rows)
    const int kchunk = wave * 4;
    const int krow_l = (lane >> 4);          // row within 4-row chunk
    const int kg     = lane & 15;            // LDS group; source group = kg ^ (row&15)
    const int vrow_l = (lane >> 3);
    const int vg     = lane & 7;

    // Q fragments (A layout: m = lane&15, k = quad*8+j)
    bf16x8 qf[4];
    const __bf16* qbase = Qp + ((size_t)h * T_SEQ + q0 + wave * 16 + r15) * HDIM;
    #pragma unroll
    for (int s = 0; s < 4; s++) qf[s] = *(const bf16x8*)(qbase + s * 32 + quad * 8);

    f32x4 oacc[8] = {};
    float mrow[4], lsum[4];
    #pragma unroll
    for (int r = 0; r < 4; r++) { mrow[r] = -1e30f; lsum[r] = 0.f; }

    const int ntk = qi + 1;

    // prologue: stage tile 0 into buffer 0
    #pragma unroll
    for (int i = 0; i < 4; i++) {
        int ck = kchunk + i;
        int krow = ck * 4 + krow_l;
        int vrow = ck * 8 + vrow_l;
        async_copy16(Kb + (size_t)krow * HDIM + (kg ^ (krow & 15)) * 8, &Ks[0][ck * 512]);
        async_copy16(Vb + (size_t)vrow * T_SEQ + (vg ^ (vrow & 7)) * 8, &Vs[0][ck * 512]);
    }

    for (int it = 0; it < ntk; it++) {
        const int buf = it & 1;
        const bool last = (it == ntk - 1);
        __syncthreads();   // stage(it) complete; prior readers of buf done

        if (!last) {
            const int tkn = (it + 1) * TK;
            const int nbuf = buf ^ 1;
            #pragma unroll
            for (int i = 0; i < 4; i++) {
                int ck = kchunk + i;
                int krow = ck * 4 + krow_l;
                int vrow = ck * 8 + vrow_l;
                async_copy16(Kb + (size_t)(tkn + krow) * HDIM + (kg ^ (krow & 15)) * 8, &Ks[nbuf][ck * 512]);
                async_copy16(Vb + (size_t)vrow * T_SEQ + tkn + (vg ^ (vrow & 7)) * 8, &Vs[nbuf][ck * 512]);
            }
        }

        // ---- S = Q K^T ----
        f32x4 sacc[4] = {};
        #pragma unroll
        for (int s = 0; s < 4; s++) {
            #pragma unroll
            for (int nt = 0; nt < 4; nt++) {
                bf16x8 kf = *(const bf16x8*)&Ks[buf][(nt * 16 + r15) * HDIM + (((s * 4 + quad) ^ r15) << 3)];
                sacc[nt] = __builtin_amdgcn_mfma_f32_16x16x32_bf16(qf[s], kf, sacc[nt], 0, 0, 0);
            }
        }

        // ---- online softmax (mask only on the diagonal tile) ----
        float alpha[4];
        #pragma unroll
        for (int r = 0; r < 4; r++) {
            if (last) {
                int qrow = q0 + wave * 16 + quad * 4 + r;
                #pragma unroll
                for (int nt = 0; nt < 4; nt++) {
                    int kcol = it * TK + nt * 16 + r15;
                    if (kcol > qrow) sacc[nt][r] = -1e30f;
                }
            }
            float tm = fmaxf(fmaxf(sacc[0][r], sacc[1][r]), fmaxf(sacc[2][r], sacc[3][r]));
            #pragma unroll
            for (int off = 1; off < 16; off <<= 1) tm = fmaxf(tm, __shfl_xor(tm, off));
            float mn = fmaxf(mrow[r], tm);
            float a = __expf(mrow[r] - mn);
            mrow[r] = mn;
            alpha[r] = a;
            float ps = 0.f;
            #pragma unroll
            for (int nt = 0; nt < 4; nt++) {
                float p = __expf(sacc[nt][r] - mn);
                sacc[nt][r] = p;              // reuse sacc as P
                ps += p;
            }
            lsum[r] = lsum[r] * a + ps;       // per-lane partial; reduced at end
        }
        #pragma unroll
        for (int nt = 0; nt < 8; nt++)
            #pragma unroll
            for (int r = 0; r < 4; r++) oacc[nt][r] *= alpha[r];

        // ---- P: C-layout -> LDS (wave-private rows, no barrier) ----
        #pragma unroll
        for (int nt = 0; nt < 4; nt++)
            #pragma unroll
            for (int r = 0; r < 4; r++)
                Ps[(wave * 16 + quad * 4 + r) * PSTR + nt * 16 + r15] = (__bf16)sacc[nt][r];

        // ---- O += P V ----
        #pragma unroll
        for (int s2 = 0; s2 < 2; s2++) {
            bf16x8 pf = *(const bf16x8*)&Ps[(wave * 16 + r15) * PSTR + s2 * 32 + quad * 8];
            #pragma unroll
            for (int nt = 0; nt < 8; nt++) {
                bf16x8 vf = *(const bf16x8*)&Vs[buf][(nt * 16 + r15) * TK + (((s2 * 4 + quad) ^ (r15 & 7)) << 3)];
                oacc[nt] = __builtin_amdgcn_mfma_f32_16x16x32_bf16(pf, vf, oacc[nt], 0, 0, 0);
            }
        }
    }

    // ---- epilogue: reduce l across 16 lanes, scale, store ----
    #pragma unroll
    for (int r = 0; r < 4; r++) {
        float l = lsum[r];
        #pragma unroll
        for (int off = 1; off < 16; off <<= 1) l += __shfl_xor(l, off);
        float inv = 1.0f / l;
        size_t row = q0 + wave * 16 + quad * 4 + r;
        #pragma unroll
        for (int nt = 0; nt < 8; nt++)
            Op[row * D_MODEL + h * HDIM + nt * 16 + r15] = (__bf16)(oacc[nt][r] * inv);
    }
}

// ---------------------------------------------------------------------------
extern "C" void kernel_launch(void* const* d_in, const int* in_sizes, int n_in,
                              void* d_out, int out_size, void* d_ws, size_t ws_size,
                              hipStream_t stream) {
    (void)in_sizes; (void)n_in; (void)out_size; (void)ws_size;
    const float* hidden = (const float*)d_in[0];
    const float* cosb   = (const float*)d_in[1];
    const float* sinb   = (const float*)d_in[2];
    const float* Wq     = (const float*)d_in[3];
    const float* Wk     = (const float*)d_in[4];
    const float* Wv     = (const float*)d_in[5];
    const float* Wo     = (const float*)d_in[6];
    const float* cwq    = (const float*)d_in[7];
    const float* cwk    = (const float*)d_in[8];
    const float* cwv    = (const float*)d_in[9];
    const float* qnw    = (const float*)d_in[10];
    const float* knw    = (const float*)d_in[11];

    const size_t NEL = (size_t)T_SEQ * D_MODEL;
    __bf16* ws = (__bf16*)d_ws;
    __bf16* h_bf   = ws + 0 * NEL;   // later reused as attn_b
    __bf16* Wq_bf  = ws + 1 * NEL;   // later reused as q_proc
    __bf16* Wk_bf  = ws + 2 * NEL;   // later reused as k_proc
    __bf16* Wv_bf  = ws + 3 * NEL;   // later reused as v_t
    __bf16* Wo_bf  = ws + 4 * NEL;   // persists to final GEMM
    __bf16* q_raw  = ws + 5 * NEL;
    __bf16* k_raw  = ws + 6 * NEL;
    __bf16* v_raw  = ws + 7 * NEL;
    __bf16* q_proc = Wq_bf;
    __bf16* k_proc = Wk_bf;
    __bf16* v_t    = Wv_bf;
    __bf16* attn_b = h_bf;
    float*  out    = (float*)d_out;

    // 0. cast fp32 inputs to bf16
    cast_kernel<<<dim3(T_SEQ, 5), 256, 0, stream>>>(hidden, Wq, Wk, Wv, Wo,
                                                    h_bf, Wq_bf, Wk_bf, Wv_bf, Wo_bf);
    // 1. q,k,v = hidden @ {Wq,Wk,Wv}^T (batched)
    gemm_bt_kernel<<<dim3(16, 16, 3), 256, 0, stream>>>(
        h_bf, Wq_bf, Wk_bf, Wv_bf, q_raw, k_raw, v_raw);
    // 2. preproc
    preproc_qk_kernel<<<dim3(T_SEQ, 2), 256, 0, stream>>>(
        q_raw, k_raw, cwq, cwk, qnw, knw, cosb, sinb, q_proc, k_proc);
    preproc_v_kernel<<<dim3(T_SEQ / 8, NH), 128, 0, stream>>>(v_raw, cwv, v_t);
    // 3. causal flash attention (double-buffered staging)
    attn_kernel<<<dim3(T_SEQ / 64, NH), 256, 0, stream>>>(q_proc, k_proc, v_t, attn_b);
    // 4. out = attn @ Wo^T, split-K x2 with fp32 atomic epilogue
    hipMemsetAsync(d_out, 0, NEL * sizeof(float), stream);
    gemm_bt_splitk_kernel<<<dim3(16, 16, 2), 256, 0, stream>>>(attn_b, Wo_bf, out);
}